// Round 8
// baseline (828.536 us; speedup 1.0000x reference)
//
#include <hip/hip_runtime.h>

#define NODES 50000
#define NEDGE 800000
#define FDIM  128

typedef __bf16 bf16x8 __attribute__((ext_vector_type(8)));
typedef float  f32x4  __attribute__((ext_vector_type(4)));

// Band coefficients B[i][k] = A[i][k] - A[i+1][k] (i=0..2), B[3] = A[3] (verified round 1).
__device__ __constant__ float BCOEF[4][9] = {
  { 0.35496460f,  0.31284160f, -0.03870412f,  0.00320868f, -1.99927e-4f,
    9.97480e-6f, -4.15015e-7f,  1.48054e-8f, -4.62272e-10f },
  { 0.27760180f,  0.12523720f, -0.11205788f,  0.03283760f, -0.00637710f,
    9.58661e-4f, -1.19074e-4f,  1.26613e-5f, -1.17878e-6f },
  { 0.16043170f, -0.08057710f, -0.08449120f,  0.08620240f, -0.04530300f,
    0.01752000f, -0.00553870f,  0.00150130f, -3.58171e-4f },
  { 0.20700190f, -0.35750170f,  0.23525320f, -0.12224870f,  0.05188000f,
   -0.01848860f,  0.00565820f, -0.00151400f,  3.59350e-4f }
};

__device__ __forceinline__ ushort bfbits(float f) {
    union { __bf16 b; ushort u; } cv; cv.b = (__bf16)f; return cv.u;
}

__device__ __forceinline__ void gload_lds16(const void* g, void* l) {
    __builtin_amdgcn_global_load_lds(
        (const __attribute__((address_space(1))) void*)(g),
        (__attribute__((address_space(3))) void*)(l),
        16, 0, 0);
}

__global__ void hist_kernel(const int* __restrict__ row, int* __restrict__ cnt, int e) {
    int i = blockIdx.x * blockDim.x + threadIdx.x;
    if (i < e) atomicAdd(&cnt[row[i]], 1);
}

// single-block exclusive scan, wave-shuffle based
__global__ __launch_bounds__(1024) void scan_kernel(
    const int* __restrict__ cnt, int* __restrict__ rowptr, int n)
{
    __shared__ int wsum[16];
    __shared__ int carry;
    const int tid = threadIdx.x, lane = tid & 63, wv = tid >> 6;
    if (tid == 0) carry = 0;
    for (int base = 0; base < n; base += 1024) {
        int i = base + tid;
        int v = (i < n) ? cnt[i] : 0;
        int x = v;
#pragma unroll
        for (int off = 1; off < 64; off <<= 1) {
            int t = __shfl_up(x, off);
            if (lane >= off) x += t;
        }
        if (lane == 63) wsum[wv] = x;
        __syncthreads();
        if (tid < 16) {
            int s = wsum[tid];
#pragma unroll
            for (int off = 1; off < 16; off <<= 1) {
                int t = __shfl_up(s, off);
                if (tid >= off) s += t;
            }
            wsum[tid] = s;
        }
        __syncthreads();
        int wbase = wv ? wsum[wv - 1] : 0;
        int c = carry;
        if (i < n) rowptr[i] = c + wbase + x - v;
        __syncthreads();
        if (tid == 1023) carry = c + wbase + x;
    }
    __syncthreads();
    if (tid == 0) rowptr[n] = carry;
}

__global__ void scatter_kernel(const int* __restrict__ row, const int* __restrict__ col,
                               const float* __restrict__ w, int* __restrict__ cursor,
                               int2* __restrict__ ev, int e) {
    int i = blockIdx.x * blockDim.x + threadIdx.x;
    if (i < e) {
        int r = row[i];
        int pos = atomicAdd(&cursor[r], 1);
        ev[pos] = make_int2(col[i], __float_as_int(w[i]));
    }
}

// X f32 [node][128] -> bf16 quarter layout [q][node][32]
__global__ void prep_xq(const float* __restrict__ X, ushort* __restrict__ Xb) {
    int t = blockIdx.x * blockDim.x + threadIdx.x;   // (q, node, c4): NODES*32 tasks
    if (t >= NODES * 32) return;
    int c4 = t & 7;
    int qn = t >> 3;
    int q = qn / NODES, node = qn - q * NODES;
    float4 v = reinterpret_cast<const float4*>(X)[(size_t)node * 32 + q * 8 + c4];
    ushort4 o;
    o.x = bfbits(v.x); o.y = bfbits(v.y); o.z = bfbits(v.z); o.w = bfbits(v.w);
    *reinterpret_cast<ushort4*>(Xb + ((size_t)q * NODES + node) * 32 + c4 * 4) = o;
}

// Weights: [mat][k][o] f32 -> Wp[mat][o][k] bf16 (transposed, un-swizzled; swizzle
// applied on the per-lane DMA source address at stage time).
__global__ void prep_w(const float* __restrict__ Wb, const float* __restrict__ Wf,
                       ushort* __restrict__ Wp) {
    int idx = blockIdx.x * blockDim.x + threadIdx.x;  // 9*128*128
    if (idx >= 9 * 128 * 128) return;
    int mat = idx >> 14, r = idx & 16383, o = r >> 7, k = r & 127;
    const float* src = (mat < 4) ? (Wb + mat * 16384 + k * 128 + o)
                                 : (Wf + (mat - 4) * 16384 + k * 128 + o);
    Wp[idx] = bfbits(*src);
}

// Quarter-feature SpMM: psi stored [q][node][32] bf16 (64 B per row-quarter).
// Wave = one (row, quarter); 4 edges in parallel (16 lanes x 1 uint each);
// quarters pinned to XCD pairs via blockIdx&7 so each 3.2 MB psi-quarter is
// L2-resident (4 MB/XCD). If the XCD round-robin assumption fails, gathers
// fall back to L3 (current behavior) -- correctness unaffected.
__global__ __launch_bounds__(256) void spmm5(
    const int* __restrict__ rowptr, const int2* __restrict__ ev,
    const ushort* __restrict__ pin,   // [4][n][32]
    const ushort* __restrict__ psub,  // same layout, or null
    ushort* __restrict__ pout,        // same layout
    float alpha, int n)
{
    int bid = blockIdx.x;
    int xcd = bid & 7;
    int q   = xcd >> 1;                       // quarter 0..3
    int rb  = (bid >> 3) * 2 + (xcd & 1);     // row-block 0..12499
    int row = rb * 4 + (threadIdx.x >> 6);
    if (row >= n) return;
    int lane = threadIdx.x & 63;
    int g = lane >> 4, c = lane & 15;
    int s = rowptr[row], e = rowptr[row + 1];
    const uint* pq = reinterpret_cast<const uint*>(pin) + (size_t)q * n * 16;
    float ax0 = 0.f, ay0 = 0.f, ax1 = 0.f, ay1 = 0.f;
    int i = s;
    for (; i + 8 <= e; i += 8) {              // 2 independent gathers in flight
        int2 e0 = ev[i + g];
        int2 e1 = ev[i + 4 + g];
        uint u0 = pq[(size_t)e0.x * 16 + c];
        uint u1 = pq[(size_t)e1.x * 16 + c];
        float w0 = __int_as_float(e0.y), w1 = __int_as_float(e1.y);
        ax0 += w0 * __uint_as_float(u0 << 16);
        ay0 += w0 * __uint_as_float(u0 & 0xffff0000u);
        ax1 += w1 * __uint_as_float(u1 << 16);
        ay1 += w1 * __uint_as_float(u1 & 0xffff0000u);
    }
    for (; i < e; i += 4) {
        int j = i + g;
        float w = 0.f; int col = 0;
        if (j < e) { int2 ed = ev[j]; col = ed.x; w = __int_as_float(ed.y); }
        uint u = pq[(size_t)col * 16 + c];
        ax0 += w * __uint_as_float(u << 16);
        ay0 += w * __uint_as_float(u & 0xffff0000u);
    }
    float ax = ax0 + ax1, ay = ay0 + ay1;
    ax += __shfl_xor(ax, 16); ay += __shfl_xor(ay, 16);
    ax += __shfl_xor(ax, 32); ay += __shfl_xor(ay, 32);
    if (g == 0) {                             // lanes 0..15 hold uint c of the quarter
        size_t off = ((size_t)q * n + row) * 16 + c;
        float rx = alpha * ax, ry = alpha * ay;
        if (psub) {
            uint su = reinterpret_cast<const uint*>(psub)[off];
            rx -= __uint_as_float(su << 16);
            ry -= __uint_as_float(su & 0xffff0000u);
        }
        union { uint u; __bf16 b[2]; } pk;
        pk.b[0] = (__bf16)rx; pk.b[1] = (__bf16)ry;
        reinterpret_cast<uint*>(pout)[off] = pk.u;
    }
}

// ---------------- MFMA epilogue (512 threads, 32-node tile) ----------------
// LDS (16B chunks): chunks 0..2559 = slots 0..3 (bands_i -> H_i) + slot 4 (X),
// [32 rows][16 chunks] each, XOR-swizzled (c ^= row&15). Chunks 2560..4607 = Wt
// [128 o][16 chunks], swizzled on read, staged linearly via global_load_lds from
// an inverse-swizzled per-lane source (rule #21).
#define RIDX(s, r, c) ((((s) << 9) + ((r) << 4) + ((c) ^ ((r) & 15))) << 3)
#define WIDX(o, c)    ((2560 + ((o) << 4) + ((c) ^ ((o) & 15))) << 3)

__global__ __launch_bounds__(512, 4) void epilogue_kernel(
    const ushort* __restrict__ Xb,      // [4][N][32] bf16 quarter layout
    const ushort* __restrict__ psi,     // [8][4][N][32] bf16 quarter layout
    const ushort* __restrict__ Wp,      // [9][128 o][128 k] bf16
    const float* __restrict__ b_band,   // [4][128]
    const float* __restrict__ b_fuse,   // [128]
    float* __restrict__ out)            // [N][128]
{
    __shared__ __align__(16) __bf16 SW[36864];   // 72 KB
    const int tid = threadIdx.x;
    const int n0 = blockIdx.x * 32;

    const int l  = tid & 63, w = tid >> 6;   // 8 waves
    const int lo = l & 15, hi = l >> 4;
    const int m  = w & 1, nb = (w >> 1) * 2; // wave -> (M-tile, 2 N-tiles)

    // preload biases
    float bb[4][2], bf[2];
#pragma unroll
    for (int i = 0; i < 4; ++i)
#pragma unroll
        for (int n = 0; n < 2; ++n) bb[i][n] = b_band[i * 128 + (nb + n) * 16 + lo];
#pragma unroll
    for (int n = 0; n < 2; ++n) bf[n] = b_fuse[(nb + n) * 16 + lo];

    // Phase 1: bands (f32 combine of bf16 X + 8 psi) -> bf16 LDS; X copied to slot 4.
    {
        int row = tid >> 4, c = tid & 15;    // chunk c = features 8c..8c+7
        int q = c >> 2, s4 = c & 3;          // quarter / uint4 within quarter
        int node = n0 + row;
        bool ok = node < NODES;
        uint4 z = make_uint4(0, 0, 0, 0);
        uint4 xq = ok ? reinterpret_cast<const uint4*>(
                            Xb + ((size_t)q * NODES + node) * 32)[s4] : z;
        *reinterpret_cast<uint4*>(&SW[RIDX(4, row, c)]) = xq;
        float f[8], bacc[4][8];
        {
            const uint* p = &xq.x;
#pragma unroll
            for (int t = 0; t < 4; ++t) {
                f[2 * t]     = __uint_as_float(p[t] << 16);
                f[2 * t + 1] = __uint_as_float(p[t] & 0xffff0000u);
            }
#pragma unroll
            for (int i = 0; i < 4; ++i)
#pragma unroll
                for (int j = 0; j < 8; ++j) bacc[i][j] = BCOEF[i][0] * f[j];
        }
#pragma unroll
        for (int k = 1; k <= 8; ++k) {
            uint4 q4 = ok ? reinterpret_cast<const uint4*>(
                psi + ((size_t)((k - 1) * 4 + q) * NODES + node) * 32)[s4] : z;
            const uint* p = &q4.x;
#pragma unroll
            for (int t = 0; t < 4; ++t) {
                f[2 * t]     = __uint_as_float(p[t] << 16);
                f[2 * t + 1] = __uint_as_float(p[t] & 0xffff0000u);
            }
#pragma unroll
            for (int i = 0; i < 4; ++i)
#pragma unroll
                for (int j = 0; j < 8; ++j) bacc[i][j] += BCOEF[i][k] * f[j];
        }
#pragma unroll
        for (int i = 0; i < 4; ++i) {
            bf16x8 bv;
#pragma unroll
            for (int j = 0; j < 8; ++j) bv[j] = (__bf16)bacc[i][j];
            *reinterpret_cast<bf16x8*>(&SW[RIDX(i, row, c)]) = bv;
        }
    }

    // 9-matrix pipeline: mats 0..3 band GEMMs (H_i written at iter i+1),
    // mats 4..8 fuse GEMM over slots {H0,H1,H2,H3,X}.
    f32x4 facc[2], hacc[2];
#pragma unroll
    for (int n = 0; n < 2; ++n) facc[n] = (f32x4){0.f, 0.f, 0.f, 0.f};

    for (int mi = 0; mi < 9; ++mi) {
        // stage Wt for matrix mi: linear LDS dest, inverse-swizzled global source
        {
            const ushort* Wm = Wp + (size_t)mi * 16384;
#pragma unroll
            for (int it = 0; it < 4; ++it) {
                int ci = it * 512 + w * 64 + l;        // 0..2047
                int o = ci >> 4, cc = ci & 15;
                int csrc = cc ^ (o & 15);
                gload_lds16(Wm + o * 128 + csrc * 8,
                            (void*)(SW + (size_t)(2560 + it * 512 + w * 64) * 8));
            }
        }
        // write H_{mi-1} (band output) into its slot while DMA is in flight
        if (mi >= 1 && mi <= 4) {
            int i = mi - 1;
#pragma unroll
            for (int n = 0; n < 2; ++n) {
#pragma unroll
                for (int r = 0; r < 4; ++r) {
                    float h = hacc[n][r] + bb[i][n];
                    h = h > 0.f ? h : 0.f;
                    int row = m * 16 + hi * 4 + r;
                    int o   = (nb + n) * 16 + lo;
                    SW[((i << 9) + (row << 4) + ((o >> 3) ^ (row & 15))) * 8 + (o & 7)] = (__bf16)h;
                }
            }
        }
        __syncthreads();   // vmcnt(0)+bar: Wt ready, H/band writes visible

        int slot = (mi < 4) ? mi : (mi - 4);
        if (mi < 4) {
#pragma unroll
            for (int n = 0; n < 2; ++n) hacc[n] = (f32x4){0.f, 0.f, 0.f, 0.f};
#pragma unroll
            for (int k = 0; k < 4; ++k) {
                bf16x8 a = *reinterpret_cast<const bf16x8*>(&SW[RIDX(slot, m * 16 + lo, k * 4 + hi)]);
#pragma unroll
                for (int n = 0; n < 2; ++n) {
                    bf16x8 b = *reinterpret_cast<const bf16x8*>(&SW[WIDX((nb + n) * 16 + lo, k * 4 + hi)]);
                    hacc[n] = __builtin_amdgcn_mfma_f32_16x16x32_bf16(a, b, hacc[n], 0, 0, 0);
                }
            }
        } else {
#pragma unroll
            for (int k = 0; k < 4; ++k) {
                bf16x8 a = *reinterpret_cast<const bf16x8*>(&SW[RIDX(slot, m * 16 + lo, k * 4 + hi)]);
#pragma unroll
                for (int n = 0; n < 2; ++n) {
                    bf16x8 b = *reinterpret_cast<const bf16x8*>(&SW[WIDX((nb + n) * 16 + lo, k * 4 + hi)]);
                    facc[n] = __builtin_amdgcn_mfma_f32_16x16x32_bf16(a, b, facc[n], 0, 0, 0);
                }
            }
        }
        __syncthreads();   // Wt/slot reads done before next stage/overwrite
    }

#pragma unroll
    for (int n = 0; n < 2; ++n) {
#pragma unroll
        for (int r = 0; r < 4; ++r) {
            int node = n0 + m * 16 + hi * 4 + r;
            if (node < NODES)
                out[(size_t)node * FDIM + (nb + n) * 16 + lo] = facc[n][r] + bf[n];
        }
    }
}

extern "C" void kernel_launch(void* const* d_in, const int* in_sizes, int n_in,
                              void* d_out, int out_size, void* d_ws, size_t ws_size,
                              hipStream_t stream) {
    (void)in_sizes; (void)n_in; (void)out_size;
    const float* X      = (const float*)d_in[0];
    const int*   erow   = (const int*)d_in[1];
    const int*   ecol   = (const int*)d_in[2];
    const float* ew     = (const float*)d_in[3];
    const float* W_band = (const float*)d_in[4];
    const float* b_band = (const float*)d_in[5];
    const float* W_fuse = (const float*)d_in[6];
    const float* b_fuse = (const float*)d_in[7];
    float* out = (float*)d_out;

    // workspace layout (bf16 psi, quarter layout)
    ushort* psi    = (ushort*)d_ws;                         // 8*[4][N][32] bf16
    ushort* Xb     = psi + (size_t)8 * NODES * FDIM;        // [4][N][32] bf16
    ushort* Wp     = Xb + (size_t)NODES * FDIM;             // 9*128*128 bf16
    int*    rowptr = (int*)(Wp + 9 * 128 * 128);            // N+1
    int*    cursor = rowptr + NODES + 1;                    // N (+1 pad for int2 align)
    int2*   ev     = (int2*)(cursor + NODES + 1);           // E (col, w)
    size_t needed = ((size_t)8 * NODES * FDIM + (size_t)NODES * FDIM + 9 * 128 * 128) * 2
                  + ((size_t)2 * NODES + 2) * 4 + (size_t)NEDGE * 8;
    if (ws_size < needed) return;

    // CSR build + precision prep
    hipMemsetAsync(cursor, 0, NODES * sizeof(int), stream);
    hist_kernel<<<(NEDGE + 255) / 256, 256, 0, stream>>>(erow, cursor, NEDGE);
    scan_kernel<<<1, 1024, 0, stream>>>(cursor, rowptr, NODES);
    hipMemcpyAsync(cursor, rowptr, NODES * sizeof(int), hipMemcpyDeviceToDevice, stream);
    scatter_kernel<<<(NEDGE + 255) / 256, 256, 0, stream>>>(erow, ecol, ew, cursor, ev, NEDGE);
    prep_xq<<<(NODES * 32 + 255) / 256, 256, 0, stream>>>(X, Xb);
    prep_w<<<(9 * 128 * 128 + 255) / 256, 256, 0, stream>>>(W_band, W_fuse, Wp);

    // Chebyshev recurrence in bf16 quarter layout / f32 accumulate.
    // grid = 12500 row-blocks x 4 quarters, XCD-pinned: 6250*8 blocks.
    spmm5<<<50000, 256, 0, stream>>>(rowptr, ev, Xb, nullptr, psi, 1.0f, NODES);
    for (int k = 2; k <= 8; ++k) {
        const ushort* pin  = psi + (size_t)(k - 2) * NODES * FDIM;
        const ushort* psub = (k == 2) ? Xb : psi + (size_t)(k - 3) * NODES * FDIM;
        ushort*       pout = psi + (size_t)(k - 1) * NODES * FDIM;
        spmm5<<<50000, 256, 0, stream>>>(rowptr, ev, pin, psub, pout, 2.0f, NODES);
    }

    // bands + band GEMMs + fuse GEMM (bf16 MFMA, f32 accum)
    epilogue_kernel<<<(NODES + 31) / 32, 512, 0, stream>>>(
        Xb, psi, Wp, b_band, b_fuse, out);
}